// Round 3
// baseline (617.382 us; speedup 1.0000x reference)
//
#include <hip/hip_runtime.h>
#include <math.h>

// ---------------------------------------------------------------------------
// myLSTMGroupCell on MI355X, f16 hi/lo split-accumulation MFMA version.
//   Stage P: transpose/convert weights to [n][k] f16 hi/lo in ws
//   Stage A: Z = [x@W | T0 | T1], T_j = h_j @ [U0[0][j] | U0[1][1-j]]   (MFMA)
//   Stage B: pre^T tiles = V^T · Z^T (operand-swapped), fused LSTM epilogue
// Group-g K-map (512): [0,256)=xw; [256,384)=T_g[0:128] (Z col k+256g);
//                      [384,512)=T_{1-g}[128:256] (Z col k+256(1-g))
// All LDS tiles are [row][32] f16 with XOR-swizzled 16B k-chunks:
//   physical_chunk = logical_chunk ^ ((row>>1)&3)   (2-way aliasing = free)
// Staging via global_load_lds writes linearly, so the swizzle is applied by
// permuting the per-lane GLOBAL source chunk (rule #21: both sides, same
// involution). Fragment reads apply the same XOR.
// ---------------------------------------------------------------------------

typedef _Float16 half_t;
typedef _Float16 half8 __attribute__((ext_vector_type(8)));
typedef float floatx4 __attribute__((ext_vector_type(4)));

#define MFMA16(a, b, c) __builtin_amdgcn_mfma_f32_16x16x32_f16((a), (b), (c), 0, 0, 0)

typedef __attribute__((address_space(3))) unsigned int lds_uint;
typedef __attribute__((address_space(1))) const unsigned int glb_uint;

__device__ __forceinline__ void gload_lds16(const void* gptr, void* ldsptr) {
    // async global->LDS: lane l writes 16B at ldsptr + l*16 (wave-uniform base)
    __builtin_amdgcn_global_load_lds((glb_uint*)gptr, (lds_uint*)ldsptr, 16, 0, 0);
}

// swizzled fragment-read offset (halfs) into a [row][32] tile
__device__ __forceinline__ int swz_ro(int row, int lq) {
    return row * 32 + ((lq ^ ((row >> 1) & 3)) << 3);
}

// ws layout in halfs
#define OFF_VTH  0u
#define OFF_VTL  4194304u
#define OFF_WTH  8388608u
#define OFF_WTL  8650752u
#define OFF_U0TH 8912896u
#define OFF_U0TL 9437184u
#define OFF_ZH   9961472u
#define OFF_ZL   16252928u

// ---------------------------------------------------------------------------
// prep_Vt: Vt row R = g*4096 + hc6*256 + hc4*64 + f*16 + hcl; Vt[R][k], K=512
//   n (within group) = hc6*64 + hc4*16 + hcl
//   k<256: Ws[f][k][g*1024+n]; k in [256,384): Ug[0][f][g][k-256][n];
//   k in [384,512): Ug[1][f][g][k-384][n].   f16 hi/lo pair.
// ---------------------------------------------------------------------------
__global__ void prep_Vt(const float* __restrict__ Ws, const float* __restrict__ Ug,
                        half_t* __restrict__ Vth, half_t* __restrict__ Vtl) {
    __shared__ half_t Lh[16][520];
    __shared__ half_t Ll[16][520];
    const int b   = blockIdx.x;            // 0..511
    const int f   = b & 3;
    const int hc4 = (b >> 2) & 3;
    const int hc6 = (b >> 4) & 15;
    const int g   = b >> 8;
    const int t   = threadIdx.x;
    const int kk  = t >> 4;                // 0..15
    const int hcl = t & 15;
    const int n   = hc6 * 64 + hc4 * 16 + hcl;

    for (int p = 0; p < 32; ++p) {
        const int k = p * 16 + kk;
        float v;
        if (k < 256)
            v = Ws[((size_t)f * 256 + k) * 2048 + g * 1024 + n];
        else if (k < 384)
            v = Ug[(((size_t)f * 2 + g) * 128 + (k - 256)) * 1024 + n];
        else
            v = Ug[(((size_t)(4 + f) * 2 + g) * 128 + (k - 384)) * 1024 + n];
        const half_t hi = (half_t)v;
        Lh[hcl][k] = hi;
        Ll[hcl][k] = (half_t)(v - (float)hi);
    }
    __syncthreads();
    const int rl = t >> 4;                 // 0..15
    const int ch = (t & 15) * 32;          // 0..480
    const size_t R0 = (size_t)b * 16;
    half_t* dh = Vth + (R0 + rl) * 512 + ch;
    half_t* dl = Vtl + (R0 + rl) * 512 + ch;
#pragma unroll
    for (int j = 0; j < 4; ++j) {
        *(half8*)&dh[j * 8] = *(const half8*)&Lh[rl][ch + j * 8];
        *(half8*)&dl[j * 8] = *(const half8*)&Ll[rl][ch + j * 8];
    }
}

// ---------------------------------------------------------------------------
// prep_ABw: stage-A weights -> [n(256)][k(1024)] f16 hi/lo
//   tgt 0: W (n=r, W[k][r]);  tgt 1+j: T_j cols: r<128 -> U0[0][j][k][r],
//   r>=128 -> U0[1][1-j][k][r-128]
// ---------------------------------------------------------------------------
__global__ void prep_ABw(const float* __restrict__ W, const float* __restrict__ U0,
                         half_t* __restrict__ Wth, half_t* __restrict__ Wtl,
                         half_t* __restrict__ U0th, half_t* __restrict__ U0tl) {
    __shared__ half_t Lh[8][1040];
    __shared__ half_t Ll[8][1040];
    const int rb  = blockIdx.x;            // 0..31
    const int tgt = blockIdx.y;            // 0..2
    const int t   = threadIdx.x;
    const int kk  = t >> 3;                // 0..31
    const int rl  = t & 7;
    const int r   = rb * 8 + rl;           // 0..255

    for (int p = 0; p < 32; ++p) {
        const int k = p * 32 + kk;
        float v;
        if (tgt == 0) {
            v = W[(size_t)k * 256 + r];
        } else {
            const int jj = tgt - 1;
            if (r < 128) v = U0[((size_t)jj * 1024 + k) * 128 + r];
            else         v = U0[((size_t)(2 + (1 - jj)) * 1024 + k) * 128 + (r - 128)];
        }
        const half_t hi = (half_t)v;
        Lh[rl][k] = hi;
        Ll[rl][k] = (half_t)(v - (float)hi);
    }
    __syncthreads();
    const int orl = t >> 5;                // 0..7
    const int ch  = (t & 31) * 32;         // 0..992
    half_t *dh, *dl;
    if (tgt == 0) { dh = Wth; dl = Wtl; }
    else { dh = U0th + (size_t)(tgt - 1) * 262144; dl = U0tl + (size_t)(tgt - 1) * 262144; }
    dh += (size_t)(rb * 8 + orl) * 1024 + ch;
    dl += (size_t)(rb * 8 + orl) * 1024 + ch;
#pragma unroll
    for (int j = 0; j < 4; ++j) {
        *(half8*)&dh[j * 8] = *(const half8*)&Lh[orl][ch + j * 8];
        *(half8*)&dl[j * 8] = *(const half8*)&Ll[orl][ch + j * 8];
    }
}

// ---------------------------------------------------------------------------
// Stage A: D[m][n] = A(x|h_j, hi/lo) @ Bw(f16 hi/lo), K=1024, BM=64, BN=256
// 4 waves 2x2: wave = 32m x 128n. Writes Zh/Zl (f16 hi/lo), ld 768.
// ---------------------------------------------------------------------------
__global__ __launch_bounds__(256, 2) void stageA_mfma(
    const float* __restrict__ x, const float* __restrict__ h,
    const half_t* __restrict__ Wth, const half_t* __restrict__ Wtl,
    const half_t* __restrict__ U0th, const half_t* __restrict__ U0tl,
    half_t* __restrict__ Zh, half_t* __restrict__ Zl) {
    __shared__ half_t Ah[64 * 32], Al[64 * 32];
    __shared__ half_t Bh[256 * 32], Bl[256 * 32];
    const int m0  = blockIdx.x * 64;
    const int seg = blockIdx.y;
    const int tid = threadIdx.x;
    const int l   = tid & 63, wid = tid >> 6;
    const int wr  = wid >> 1, wcn = wid & 1;

    const float* Asrc; int ldA;
    if (seg == 0) { Asrc = x; ldA = 1024; }
    else          { Asrc = h + (seg - 1) * 1024; ldA = 2048; }
    const half_t *Bsh, *Bsl;
    if (seg == 0) { Bsh = Wth; Bsl = Wtl; }
    else { Bsh = U0th + (size_t)(seg - 1) * 262144; Bsl = U0tl + (size_t)(seg - 1) * 262144; }

    const int arow = tid >> 2, au = tid & 3;
    const int aqp  = (au ^ ((tid >> 3) & 3));           // physical chunk for A ds_write
    const float* aptr = Asrc + (size_t)(m0 + arow) * ldA + au * 8;
    const int lrow = l >> 2;
    const int lks  = ((l & 3) ^ ((l >> 3) & 3)) << 3;   // swizzled global k-chunk (halfs)

    floatx4 acc[2][8] = {};

#pragma unroll 1
    for (int kt = 0; kt < 1024; kt += 32) {
        __syncthreads();
        // A: fp32 -> f16 hi/lo, reg-staged, swizzled ds_write
        const float4 v0 = *(const float4*)(aptr + kt);
        const float4 v1 = *(const float4*)(aptr + kt + 4);
        const float va[8] = {v0.x, v0.y, v0.z, v0.w, v1.x, v1.y, v1.z, v1.w};
        half8 hv, lv;
#pragma unroll
        for (int j = 0; j < 8; ++j) {
            const half_t hi = (half_t)va[j];
            hv[j] = hi;
            lv[j] = (half_t)(va[j] - (float)hi);
        }
        *(half8*)&Ah[arow * 32 + aqp * 8] = hv;
        *(half8*)&Al[arow * 32 + aqp * 8] = lv;
        // B: 256x32 hi/lo via global_load_lds (pre-swizzled source chunk)
#pragma unroll
        for (int q = 0; q < 4; ++q) {
            const int i = wid * 4 + q;
            const size_t grow = (size_t)(i * 16 + lrow) * 1024 + kt + lks;
            gload_lds16(Bsh + grow, &Bh[i * 512]);
            gload_lds16(Bsl + grow, &Bl[i * 512]);
        }
        __syncthreads();

        half8 ah[2], al[2];
#pragma unroll
        for (int mt = 0; mt < 2; ++mt) {
            const int ro = swz_ro(wr * 32 + mt * 16 + (l & 15), l >> 4);
            ah[mt] = *(const half8*)&Ah[ro];
            al[mt] = *(const half8*)&Al[ro];
        }
#pragma unroll
        for (int nt = 0; nt < 8; ++nt) {
            const int ro = swz_ro(wcn * 128 + nt * 16 + (l & 15), l >> 4);
            const half8 bh = *(const half8*)&Bh[ro];
            const half8 bl = *(const half8*)&Bl[ro];
#pragma unroll
            for (int mt = 0; mt < 2; ++mt) {
                acc[mt][nt] = MFMA16(ah[mt], bh, acc[mt][nt]);
                acc[mt][nt] = MFMA16(ah[mt], bl, acc[mt][nt]);
                acc[mt][nt] = MFMA16(al[mt], bh, acc[mt][nt]);
            }
        }
    }
    // epilogue: write Z as f16 hi/lo
#pragma unroll
    for (int mt = 0; mt < 2; ++mt)
#pragma unroll
        for (int nt = 0; nt < 8; ++nt)
#pragma unroll
            for (int r = 0; r < 4; ++r) {
                const int row = m0 + wr * 32 + mt * 16 + (l >> 4) * 4 + r;
                const int col = seg * 256 + wcn * 128 + nt * 16 + (l & 15);
                const float v = acc[mt][nt][r];
                const half_t hi = (half_t)v;
                Zh[(size_t)row * 768 + col] = hi;
                Zl[(size_t)row * 768 + col] = (half_t)(v - (float)hi);
            }
}

// ---------------------------------------------------------------------------
// Stage B (operand-swapped): D[n'][m] = V^T (hi/lo) . Z^T (hi/lo), K=512
// block: n'=256 x m=128; waves 2x2 (wr: 128 n', wc: 64 m)
// n'_local = hc4*64 + f*16 + hcl  -> every lane holds all 4 gates for its
// (hc, m) pairs -> fully in-register fused LSTM epilogue.
// ---------------------------------------------------------------------------
__global__ __launch_bounds__(256, 2) void stageB_mfma(
    const half_t* __restrict__ Vth, const half_t* __restrict__ Vtl,
    const half_t* __restrict__ Zh, const half_t* __restrict__ Zl,
    const float* __restrict__ bias, const float* __restrict__ c,
    float* __restrict__ out) {
    __shared__ half_t Wh[256 * 32], Wl[256 * 32];
    __shared__ half_t Th[128 * 32], Tl[128 * 32];
    const int m0  = blockIdx.x * 128;
    const int hc6 = blockIdx.y;
    const int g   = blockIdx.z;
    const int tid = threadIdx.x;
    const int l   = tid & 63, wid = tid >> 6;
    const int wr  = wid >> 1, wc = wid & 1;
    const size_t vbase = ((size_t)g * 16 + hc6) * 256;
    const int lrow = l >> 2;
    const int lks  = ((l & 3) ^ ((l >> 3) & 3)) << 3;   // swizzled global k-chunk

    floatx4 acc[8][4] = {};            // [n' 16-tile][m 16-tile]

#pragma unroll 1
    for (int kt = 0; kt < 512; kt += 32) {
        const int zcol = (kt < 256) ? kt : ((kt < 384) ? kt + (g << 8) : kt + ((1 - g) << 8));
        __syncthreads();
        // A (weights V^T): 16 chunks of 16 rows
#pragma unroll
        for (int q = 0; q < 4; ++q) {
            const int i = wid * 4 + q;
            const size_t grow = (vbase + i * 16 + lrow) * 512 + kt + lks;
            gload_lds16(Vth + grow, &Wh[i * 512]);
            gload_lds16(Vtl + grow, &Wl[i * 512]);
        }
        // B (Z^T): 8 chunks of 16 rows
#pragma unroll
        for (int q = 0; q < 2; ++q) {
            const int i = wid * 2 + q;
            const size_t grow = (size_t)(m0 + i * 16 + lrow) * 768 + zcol + lks;
            gload_lds16(Zh + grow, &Th[i * 512]);
            gload_lds16(Zl + grow, &Tl[i * 512]);
        }
        __syncthreads();

        half8 bh[4], bl[4];
#pragma unroll
        for (int mt = 0; mt < 4; ++mt) {
            const int ro = swz_ro(wc * 64 + mt * 16 + (l & 15), l >> 4);
            bh[mt] = *(const half8*)&Th[ro];
            bl[mt] = *(const half8*)&Tl[ro];
        }
#pragma unroll
        for (int nt = 0; nt < 8; ++nt) {
            const int ro = swz_ro(wr * 128 + nt * 16 + (l & 15), l >> 4);
            const half8 afh = *(const half8*)&Wh[ro];
            const half8 afl = *(const half8*)&Wl[ro];
#pragma unroll
            for (int mt = 0; mt < 4; ++mt) {
                acc[nt][mt] = MFMA16(afh, bh[mt], acc[nt][mt]);
                acc[nt][mt] = MFMA16(afh, bl[mt], acc[nt][mt]);
                acc[nt][mt] = MFMA16(afl, bh[mt], acc[nt][mt]);
            }
        }
    }

    // fused LSTM epilogue (all 4 gates in-lane)
    const size_t outH = (size_t)8192 * 2048;
#pragma unroll
    for (int h4 = 0; h4 < 2; ++h4)
#pragma unroll
        for (int r = 0; r < 4; ++r) {
            const int hc   = hc6 * 64 + (wr * 2 + h4) * 16 + (l >> 4) * 4 + r;
            const int hcol = g * 1024 + hc;
            const float bf = bias[hcol];
            const float bi = bias[2048 + hcol];
            const float bo = bias[4096 + hcol];
            const float bg = bias[6144 + hcol];
#pragma unroll
            for (int mt = 0; mt < 4; ++mt) {
                const int m = m0 + wc * 64 + mt * 16 + (l & 15);
                const float pf = acc[h4 * 4 + 0][mt][r] + bf;
                const float pi = acc[h4 * 4 + 1][mt][r] + bi;
                const float po = acc[h4 * 4 + 2][mt][r] + bo;
                const float pg = acc[h4 * 4 + 3][mt][r] + bg;
                const float fg = 1.f / (1.f + __expf(-pf));
                const float ig = 1.f / (1.f + __expf(-pi));
                const float og = 1.f / (1.f + __expf(-po));
                const float gg = 2.f / (1.f + __expf(-2.f * pg)) - 1.f;
                const float cv = c[(size_t)m * 2048 + hcol];
                const float cn = fg * cv + ig * gg;
                const float th = 2.f / (1.f + __expf(-2.f * cn)) - 1.f;
                out[(size_t)m * 2048 + hcol]        = cn;
                out[outH + (size_t)m * 2048 + hcol] = og * th;
            }
        }
}

// ---------------------------------------------------------------------------
extern "C" void kernel_launch(void* const* d_in, const int* in_sizes, int n_in,
                              void* d_out, int out_size, void* d_ws, size_t ws_size,
                              hipStream_t stream) {
    const float* x    = (const float*)d_in[0];   // (8192, 1024)
    const float* h    = (const float*)d_in[1];   // (8192, 2048)
    const float* c    = (const float*)d_in[2];   // (8192, 2048)
    const float* W    = (const float*)d_in[3];   // (1024, 256)
    const float* Ws   = (const float*)d_in[4];   // (4, 256, 2048)
    const float* U0   = (const float*)d_in[5];   // (2, 2, 1024, 128)
    const float* Ug   = (const float*)d_in[6];   // (2, 4, 2, 128, 1024)
    const float* bias = (const float*)d_in[7];   // (4, 2048)
    float* out = (float*)d_out;                  // [c_next | h_next]

    half_t* wsp  = (half_t*)d_ws;                // needs ~43 MB
    half_t* Vth  = wsp + OFF_VTH;
    half_t* Vtl  = wsp + OFF_VTL;
    half_t* Wth  = wsp + OFF_WTH;
    half_t* Wtl  = wsp + OFF_WTL;
    half_t* U0th = wsp + OFF_U0TH;
    half_t* U0tl = wsp + OFF_U0TL;
    half_t* Zh   = wsp + OFF_ZH;
    half_t* Zl   = wsp + OFF_ZL;

    prep_Vt<<<512, 256, 0, stream>>>(Ws, Ug, Vth, Vtl);
    prep_ABw<<<dim3(32, 3), 256, 0, stream>>>(W, U0, Wth, Wtl, U0th, U0tl);
    stageA_mfma<<<dim3(128, 3), 256, 0, stream>>>(x, h, Wth, Wtl, U0th, U0tl, Zh, Zl);
    stageB_mfma<<<dim3(64, 16, 2), 256, 0, stream>>>(Vth, Vtl, Zh, Zl, bias, c, out);
}

// Round 5
// 568.707 us; speedup vs baseline: 1.0856x; 1.0856x over previous
//
#include <hip/hip_runtime.h>
#include <math.h>

// ---------------------------------------------------------------------------
// myLSTMGroupCell on MI355X, f16 hi/lo split-accumulation MFMA version.
//   Stage P: transpose/convert weights to [n][k] f16 hi/lo in ws
//   Stage A: Z = [x@W | T0 | T1], T_j = h_j @ [U0[0][j] | U0[1][1-j]]   (MFMA)
//   Stage B: pre^T tiles = V^T · Z^T (operand-swapped), counted-vmcnt 3-slot
//            LDS ring pipeline (T3/T4), fused in-register LSTM epilogue.
// Group-g K-map (512): [0,256)=xw; [256,384)=T_g[0:128] (Z col k+256g);
//                      [384,512)=T_{1-g}[128:256] (Z col k+256(1-g))
// All LDS tiles are [row][32] f16 with XOR-swizzled 16B k-chunks:
//   physical_chunk = logical_chunk ^ ((row>>1)&3)   (2-way aliasing = free)
// global_load_lds writes linearly -> swizzle applied by permuting the per-lane
// GLOBAL source chunk (rule #21); fragment reads apply the same XOR.
// HW-verified round-3: passed, absmax 0.0156, SQ_LDS_BANK_CONFLICT = 0.
// Round-4 design (this file, + stageA prefetch) never ran: infra failure.
// ---------------------------------------------------------------------------

typedef _Float16 half_t;
typedef _Float16 half8 __attribute__((ext_vector_type(8)));
typedef float floatx4 __attribute__((ext_vector_type(4)));

#define MFMA16(a, b, c) __builtin_amdgcn_mfma_f32_16x16x32_f16((a), (b), (c), 0, 0, 0)

typedef __attribute__((address_space(3))) unsigned int lds_uint;
typedef __attribute__((address_space(1))) const unsigned int glb_uint;

__device__ __forceinline__ void gload_lds16(const void* gptr, void* ldsptr) {
    // async global->LDS: lane l writes 16B at ldsptr + l*16 (wave-uniform base)
    __builtin_amdgcn_global_load_lds((glb_uint*)gptr, (lds_uint*)ldsptr, 16, 0, 0);
}

// swizzled fragment-read offset (halfs) into a [row][32] tile
__device__ __forceinline__ int swz_ro(int row, int lq) {
    return row * 32 + ((lq ^ ((row >> 1) & 3)) << 3);
}

// ws layout in halfs
#define OFF_VTH  0u
#define OFF_VTL  4194304u
#define OFF_WTH  8388608u
#define OFF_WTL  8650752u
#define OFF_U0TH 8912896u
#define OFF_U0TL 9437184u
#define OFF_ZH   9961472u
#define OFF_ZL   16252928u

// ---------------------------------------------------------------------------
// prep_Vt: Vt row R = g*4096 + hc6*256 + hc4*64 + f*16 + hcl; Vt[R][k], K=512
// ---------------------------------------------------------------------------
__global__ void prep_Vt(const float* __restrict__ Ws, const float* __restrict__ Ug,
                        half_t* __restrict__ Vth, half_t* __restrict__ Vtl) {
    __shared__ half_t Lh[16][520];
    __shared__ half_t Ll[16][520];
    const int b   = blockIdx.x;            // 0..511
    const int f   = b & 3;
    const int hc4 = (b >> 2) & 3;
    const int hc6 = (b >> 4) & 15;
    const int g   = b >> 8;
    const int t   = threadIdx.x;
    const int kk  = t >> 4;                // 0..15
    const int hcl = t & 15;
    const int n   = hc6 * 64 + hc4 * 16 + hcl;

    for (int p = 0; p < 32; ++p) {
        const int k = p * 16 + kk;
        float v;
        if (k < 256)
            v = Ws[((size_t)f * 256 + k) * 2048 + g * 1024 + n];
        else if (k < 384)
            v = Ug[(((size_t)f * 2 + g) * 128 + (k - 256)) * 1024 + n];
        else
            v = Ug[(((size_t)(4 + f) * 2 + g) * 128 + (k - 384)) * 1024 + n];
        const half_t hi = (half_t)v;
        Lh[hcl][k] = hi;
        Ll[hcl][k] = (half_t)(v - (float)hi);
    }
    __syncthreads();
    const int rl = t >> 4;                 // 0..15
    const int ch = (t & 15) * 32;          // 0..480
    const size_t R0 = (size_t)b * 16;
    half_t* dh = Vth + (R0 + rl) * 512 + ch;
    half_t* dl = Vtl + (R0 + rl) * 512 + ch;
#pragma unroll
    for (int j = 0; j < 4; ++j) {
        *(half8*)&dh[j * 8] = *(const half8*)&Lh[rl][ch + j * 8];
        *(half8*)&dl[j * 8] = *(const half8*)&Ll[rl][ch + j * 8];
    }
}

// ---------------------------------------------------------------------------
// prep_ABw: stage-A weights -> [n(256)][k(1024)] f16 hi/lo
// ---------------------------------------------------------------------------
__global__ void prep_ABw(const float* __restrict__ W, const float* __restrict__ U0,
                         half_t* __restrict__ Wth, half_t* __restrict__ Wtl,
                         half_t* __restrict__ U0th, half_t* __restrict__ U0tl) {
    __shared__ half_t Lh[8][1040];
    __shared__ half_t Ll[8][1040];
    const int rb  = blockIdx.x;            // 0..31
    const int tgt = blockIdx.y;            // 0..2
    const int t   = threadIdx.x;
    const int kk  = t >> 3;                // 0..31
    const int rl  = t & 7;
    const int r   = rb * 8 + rl;           // 0..255

    for (int p = 0; p < 32; ++p) {
        const int k = p * 32 + kk;
        float v;
        if (tgt == 0) {
            v = W[(size_t)k * 256 + r];
        } else {
            const int jj = tgt - 1;
            if (r < 128) v = U0[((size_t)jj * 1024 + k) * 128 + r];
            else         v = U0[((size_t)(2 + (1 - jj)) * 1024 + k) * 128 + (r - 128)];
        }
        const half_t hi = (half_t)v;
        Lh[rl][k] = hi;
        Ll[rl][k] = (half_t)(v - (float)hi);
    }
    __syncthreads();
    const int orl = t >> 5;                // 0..7
    const int ch  = (t & 31) * 32;         // 0..992
    half_t *dh, *dl;
    if (tgt == 0) { dh = Wth; dl = Wtl; }
    else { dh = U0th + (size_t)(tgt - 1) * 262144; dl = U0tl + (size_t)(tgt - 1) * 262144; }
    dh += (size_t)(rb * 8 + orl) * 1024 + ch;
    dl += (size_t)(rb * 8 + orl) * 1024 + ch;
#pragma unroll
    for (int j = 0; j < 4; ++j) {
        *(half8*)&dh[j * 8] = *(const half8*)&Lh[orl][ch + j * 8];
        *(half8*)&dl[j * 8] = *(const half8*)&Ll[orl][ch + j * 8];
    }
}

// ---------------------------------------------------------------------------
// Stage A: D[m][n] = A(x|h_j, hi/lo) @ Bw(f16 hi/lo), K=1024, BM=64, BN=256
// Round-5 tweak: B gloads issued first, next-step A float4s prefetched before
// barrier #2 so the A global latency drains in parallel with the B gloads
// (round-3 exposed it serially at the top of every K-step).
// ---------------------------------------------------------------------------
__global__ __launch_bounds__(256, 2) void stageA_mfma(
    const float* __restrict__ x, const float* __restrict__ h,
    const half_t* __restrict__ Wth, const half_t* __restrict__ Wtl,
    const half_t* __restrict__ U0th, const half_t* __restrict__ U0tl,
    half_t* __restrict__ Zh, half_t* __restrict__ Zl) {
    __shared__ half_t Ah[64 * 32], Al[64 * 32];
    __shared__ half_t Bh[256 * 32], Bl[256 * 32];
    const int m0  = blockIdx.x * 64;
    const int seg = blockIdx.y;
    const int tid = threadIdx.x;
    const int l   = tid & 63, wid = tid >> 6;
    const int wr  = wid >> 1, wcn = wid & 1;

    const float* Asrc; int ldA;
    if (seg == 0) { Asrc = x; ldA = 1024; }
    else          { Asrc = h + (seg - 1) * 1024; ldA = 2048; }
    const half_t *Bsh, *Bsl;
    if (seg == 0) { Bsh = Wth; Bsl = Wtl; }
    else { Bsh = U0th + (size_t)(seg - 1) * 262144; Bsl = U0tl + (size_t)(seg - 1) * 262144; }

    const int arow = tid >> 2, au = tid & 3;
    const int aqp  = (au ^ ((tid >> 3) & 3));           // physical chunk for A ds_write
    const float* aptr = Asrc + (size_t)(m0 + arow) * ldA + au * 8;
    const int lrow = l >> 2;
    const int lks  = ((l & 3) ^ ((l >> 3) & 3)) << 3;   // swizzled global k-chunk (halfs)

    floatx4 acc[2][8] = {};

    float4 v0 = *(const float4*)(aptr);                 // step-0 A prefetch
    float4 v1 = *(const float4*)(aptr + 4);

#pragma unroll 1
    for (int kt = 0; kt < 1024; kt += 32) {
        __syncthreads();
        // B: 256x32 hi/lo via global_load_lds (pre-swizzled source chunk)
#pragma unroll
        for (int q = 0; q < 4; ++q) {
            const int i = wid * 4 + q;
            const size_t grow = (size_t)(i * 16 + lrow) * 1024 + kt + lks;
            gload_lds16(Bsh + grow, &Bh[i * 512]);
            gload_lds16(Bsl + grow, &Bl[i * 512]);
        }
        // A: fp32 -> f16 hi/lo, reg-staged, swizzled ds_write
        const float va[8] = {v0.x, v0.y, v0.z, v0.w, v1.x, v1.y, v1.z, v1.w};
        half8 hv, lv;
#pragma unroll
        for (int j = 0; j < 8; ++j) {
            const half_t hi = (half_t)va[j];
            hv[j] = hi;
            lv[j] = (half_t)(va[j] - (float)hi);
        }
        *(half8*)&Ah[arow * 32 + aqp * 8] = hv;
        *(half8*)&Al[arow * 32 + aqp * 8] = lv;
        // prefetch next step's A (drains with the B gloads at the barrier)
        if (kt + 32 < 1024) {
            v0 = *(const float4*)(aptr + kt + 32);
            v1 = *(const float4*)(aptr + kt + 36);
        }
        __syncthreads();

        half8 ah[2], al[2];
#pragma unroll
        for (int mt = 0; mt < 2; ++mt) {
            const int ro = swz_ro(wr * 32 + mt * 16 + (l & 15), l >> 4);
            ah[mt] = *(const half8*)&Ah[ro];
            al[mt] = *(const half8*)&Al[ro];
        }
#pragma unroll
        for (int nt = 0; nt < 8; ++nt) {
            const int ro = swz_ro(wcn * 128 + nt * 16 + (l & 15), l >> 4);
            const half8 bh = *(const half8*)&Bh[ro];
            const half8 bl = *(const half8*)&Bl[ro];
#pragma unroll
            for (int mt = 0; mt < 2; ++mt) {
                acc[mt][nt] = MFMA16(ah[mt], bh, acc[mt][nt]);
                acc[mt][nt] = MFMA16(ah[mt], bl, acc[mt][nt]);
                acc[mt][nt] = MFMA16(al[mt], bh, acc[mt][nt]);
            }
        }
    }
#pragma unroll
    for (int mt = 0; mt < 2; ++mt)
#pragma unroll
        for (int nt = 0; nt < 8; ++nt)
#pragma unroll
            for (int r = 0; r < 4; ++r) {
                const int row = m0 + wr * 32 + mt * 16 + (l >> 4) * 4 + r;
                const int col = seg * 256 + wcn * 128 + nt * 16 + (l & 15);
                const float v = acc[mt][nt][r];
                const half_t hi = (half_t)v;
                Zh[(size_t)row * 768 + col] = hi;
                Zl[(size_t)row * 768 + col] = (half_t)(v - (float)hi);
            }
}

// ---------------------------------------------------------------------------
// Stage B: D[n'][m] = V^T (hi/lo) . Z^T (hi/lo), K=512, counted-vmcnt pipeline.
// Block: 512 thr (8 waves 2x4), tile 256 n' x 128 m, BK=32, 16 K-steps.
// LDS: 3-slot ring, slot = Ah[256x32] Al[256x32] Bh[128x32] Bl[128x32] = 48KB.
// Pipeline: stage(s+2) issued, then s_waitcnt vmcnt(12) (slot s done, s+1/s+2
// in flight), raw s_barrier, compute, raw s_barrier. Never drains to 0 mid-loop.
// Wave wid: wr=wid>>2 (n' half, 128), wc=wid&3 (m quarter, 32).
// n'_local = hc4*64 + f*16 + hcl -> lane holds all 4 gates -> in-reg epilogue.
// ---------------------------------------------------------------------------
__global__ __launch_bounds__(512, 2) void stageB_mfma(
    const half_t* __restrict__ Vth, const half_t* __restrict__ Vtl,
    const half_t* __restrict__ Zh, const half_t* __restrict__ Zl,
    const float* __restrict__ bias, const float* __restrict__ c,
    float* __restrict__ out) {
    __shared__ half_t lds[3 * 24576];      // 144 KB
    const int tid = threadIdx.x;
    const int l   = tid & 63, wid = tid >> 6;
    const int wr  = wid >> 2, wc = wid & 3;

    // XCD-chunked bijective swizzle (nwg=2048, %8==0): each XCD gets 256
    // consecutive lin ids = 8 m-blocks sharing Z panels (3.2MB < 4MB L2).
    const int lin = (blockIdx.x & 7) * 256 + (blockIdx.x >> 3);
    const int mb  = lin >> 5;              // 0..63
    const int rem = lin & 31;
    const int g   = rem >> 4, hc6 = rem & 15;
    const int m0  = mb * 128;
    const size_t vbase = ((size_t)g * 16 + hc6) * 256;
    const int lrow = l >> 2;
    const int lks  = ((l & 3) ^ ((l >> 3) & 3)) << 3;  // swizzled global k-chunk

    // stage slot s: issue 6 global_load_lds per wave (A hi x2, A lo x2, B hi, B lo)
    auto stage = [&](int s) {
        const int kt   = s * 32;
        const int zcol = (kt < 256) ? kt : ((kt < 384) ? kt + (g << 8) : kt + ((1 - g) << 8));
        half_t* base = &lds[(s % 3) * 24576];
#pragma unroll
        for (int q = 0; q < 2; ++q) {
            const int i = wid * 2 + q;
            const size_t grow = (vbase + i * 16 + lrow) * 512 + kt + lks;
            gload_lds16(Vth + grow, base + i * 512);
        }
#pragma unroll
        for (int q = 0; q < 2; ++q) {
            const int i = wid * 2 + q;
            const size_t grow = (vbase + i * 16 + lrow) * 512 + kt + lks;
            gload_lds16(Vtl + grow, base + 8192 + i * 512);
        }
        {
            const size_t grow = (size_t)(m0 + wid * 16 + lrow) * 768 + zcol + lks;
            gload_lds16(Zh + grow, base + 16384 + wid * 512);
            gload_lds16(Zl + grow, base + 20480 + wid * 512);
        }
    };

    floatx4 acc[8][2] = {};                // [n' 16-tile][m 16-tile]

    stage(0);
    stage(1);
#pragma unroll 1
    for (int s = 0; s < 16; ++s) {
        if (s < 14) {
            stage(s + 2);
            asm volatile("s_waitcnt vmcnt(12)" ::: "memory");
        } else if (s == 14) {
            asm volatile("s_waitcnt vmcnt(6)" ::: "memory");
        } else {
            asm volatile("s_waitcnt vmcnt(0)" ::: "memory");
        }
        __builtin_amdgcn_s_barrier();

        const half_t* base = &lds[(s % 3) * 24576];
        half8 bh[2], bl[2];
#pragma unroll
        for (int mt = 0; mt < 2; ++mt) {
            const int ro = swz_ro(wc * 32 + mt * 16 + (l & 15), l >> 4);
            bh[mt] = *(const half8*)&base[16384 + ro];
            bl[mt] = *(const half8*)&base[20480 + ro];
        }
        __builtin_amdgcn_s_setprio(1);
#pragma unroll
        for (int nt = 0; nt < 8; ++nt) {
            const int ro = swz_ro(wr * 128 + nt * 16 + (l & 15), l >> 4);
            const half8 ah = *(const half8*)&base[ro];
            const half8 al = *(const half8*)&base[8192 + ro];
#pragma unroll
            for (int mt = 0; mt < 2; ++mt) {
                acc[nt][mt] = MFMA16(ah, bh[mt], acc[nt][mt]);
                acc[nt][mt] = MFMA16(ah, bl[mt], acc[nt][mt]);
                acc[nt][mt] = MFMA16(al, bh[mt], acc[nt][mt]);
            }
        }
        __builtin_amdgcn_s_setprio(0);
        __builtin_amdgcn_s_barrier();
    }

    // fused LSTM epilogue, float4-vectorized (fixes round-3's 4.8x write amp)
    const size_t outH = (size_t)8192 * 2048;
#pragma unroll
    for (int h4 = 0; h4 < 2; ++h4) {
        const int hbase = g * 1024 + hc6 * 64 + (wr * 2 + h4) * 16 + (l >> 4) * 4;
        const float4 b0 = *(const float4*)(bias + 0 * 2048 + hbase);
        const float4 b1 = *(const float4*)(bias + 1 * 2048 + hbase);
        const float4 b2 = *(const float4*)(bias + 2 * 2048 + hbase);
        const float4 b3 = *(const float4*)(bias + 3 * 2048 + hbase);
        const float* b0p = (const float*)&b0;
        const float* b1p = (const float*)&b1;
        const float* b2p = (const float*)&b2;
        const float* b3p = (const float*)&b3;
#pragma unroll
        for (int mt = 0; mt < 2; ++mt) {
            const int m = m0 + wc * 32 + mt * 16 + (l & 15);
            const float4 cv = *(const float4*)(c + (size_t)m * 2048 + hbase);
            const float* cvp = (const float*)&cv;
            float4 co, ho;
            float* cop = (float*)&co;
            float* hop = (float*)&ho;
#pragma unroll
            for (int r = 0; r < 4; ++r) {
                const float pf = acc[h4 * 4 + 0][mt][r] + b0p[r];
                const float pi = acc[h4 * 4 + 1][mt][r] + b1p[r];
                const float po = acc[h4 * 4 + 2][mt][r] + b2p[r];
                const float pg = acc[h4 * 4 + 3][mt][r] + b3p[r];
                const float fg = 1.f / (1.f + __expf(-pf));
                const float ig = 1.f / (1.f + __expf(-pi));
                const float og = 1.f / (1.f + __expf(-po));
                const float gg = 2.f / (1.f + __expf(-2.f * pg)) - 1.f;
                const float cn = fg * cvp[r] + ig * gg;
                const float th = 2.f / (1.f + __expf(-2.f * cn)) - 1.f;
                cop[r] = cn;
                hop[r] = og * th;
            }
            *(float4*)(out +        (size_t)m * 2048 + hbase) = co;
            *(float4*)(out + outH + (size_t)m * 2048 + hbase) = ho;
        }
    }
}

// ---------------------------------------------------------------------------
extern "C" void kernel_launch(void* const* d_in, const int* in_sizes, int n_in,
                              void* d_out, int out_size, void* d_ws, size_t ws_size,
                              hipStream_t stream) {
    const float* x    = (const float*)d_in[0];   // (8192, 1024)
    const float* h    = (const float*)d_in[1];   // (8192, 2048)
    const float* c    = (const float*)d_in[2];   // (8192, 2048)
    const float* W    = (const float*)d_in[3];   // (1024, 256)
    const float* Ws   = (const float*)d_in[4];   // (4, 256, 2048)
    const float* U0   = (const float*)d_in[5];   // (2, 2, 1024, 128)
    const float* Ug   = (const float*)d_in[6];   // (2, 4, 2, 128, 1024)
    const float* bias = (const float*)d_in[7];   // (4, 2048)
    float* out = (float*)d_out;                  // [c_next | h_next]

    half_t* wsp  = (half_t*)d_ws;                // needs ~43 MB
    half_t* Vth  = wsp + OFF_VTH;
    half_t* Vtl  = wsp + OFF_VTL;
    half_t* Wth  = wsp + OFF_WTH;
    half_t* Wtl  = wsp + OFF_WTL;
    half_t* U0th = wsp + OFF_U0TH;
    half_t* U0tl = wsp + OFF_U0TL;
    half_t* Zh   = wsp + OFF_ZH;
    half_t* Zl   = wsp + OFF_ZL;

    prep_Vt<<<512, 256, 0, stream>>>(Ws, Ug, Vth, Vtl);
    prep_ABw<<<dim3(32, 3), 256, 0, stream>>>(W, U0, Wth, Wtl, U0th, U0tl);
    stageA_mfma<<<dim3(128, 3), 256, 0, stream>>>(x, h, Wth, Wtl, U0th, U0tl, Zh, Zl);
    stageB_mfma<<<2048, 512, 0, stream>>>(Vth, Vtl, Zh, Zl, bias, c, out);
}